// Round 15
// baseline (300.869 us; speedup 1.0000x reference)
//
#include <hip/hip_runtime.h>
#include <hip/hip_bf16.h>

typedef __bf16 bf16_t;
typedef __bf16 bf16x8 __attribute__((ext_vector_type(8)));
typedef float f32x4 __attribute__((ext_vector_type(4)));
typedef unsigned int uint32x2 __attribute__((ext_vector_type(2)));
typedef unsigned int uint32x4 __attribute__((ext_vector_type(4)));

#define B_SZ 4
#define SEQ 2048
#define NH 16
#define DH 64
#define DM 1024
#define RSQ (3 * DM)

// async global->LDS, 16B per lane. LDS dest = wave-uniform base + lane*16.
__device__ __forceinline__ void gload_lds16(const bf16_t* g, bf16_t* l) {
  __builtin_amdgcn_global_load_lds(
      (const __attribute__((address_space(1))) unsigned int*)g,
      (__attribute__((address_space(3))) unsigned int*)l, 16, 0, 0);
}

__device__ __forceinline__ unsigned lds_b32addr(void* p) {
  return (unsigned)(uintptr_t)(__attribute__((address_space(3))) void*)p;
}

// ---------------------------------------------------------------------------
// Merged prep: [0,8192) fp32->bf16 convert of x; [8192,11264) transpose+scale
// w_qkv; [11264,12288) transpose w_o. One launch instead of three.
// ---------------------------------------------------------------------------
__global__ __launch_bounds__(256) void prep_kernel(
    const float* __restrict__ x, bf16_t* __restrict__ xb,
    const float* __restrict__ w_qkv, bf16_t* __restrict__ wqkvt,
    const float* __restrict__ w_o, bf16_t* __restrict__ wot, float qscale) {
  __shared__ float tile[32][33];
  const int bid = blockIdx.x;
  if (bid < 8192) {
    int i = (bid * 256 + threadIdx.x) * 4;
    float4 v = *reinterpret_cast<const float4*>(x + i);
    bf16_t o[4] = {(bf16_t)v.x, (bf16_t)v.y, (bf16_t)v.z, (bf16_t)v.w};
    *reinterpret_cast<uint2*>(xb + i) = *reinterpret_cast<const uint2*>(o);
    return;
  }
  const float* in;
  bf16_t* outT;
  int K = 1024, N, n0, k0, scale_cols;
  if (bid < 8192 + 3072) {
    int i = bid - 8192;
    in = w_qkv; outT = wqkvt; N = 3072;
    n0 = (i % 96) * 32; k0 = (i / 96) * 32; scale_cols = 1024;
  } else {
    int i = bid - 8192 - 3072;
    in = w_o; outT = wot; N = 1024;
    n0 = (i % 32) * 32; k0 = (i / 32) * 32; scale_cols = 0;
  }
  const int tx = threadIdx.x & 31;
  const int ty = threadIdx.x >> 5;  // 0..7
#pragma unroll
  for (int j = 0; j < 4; ++j)
    tile[ty + j * 8][tx] = in[(size_t)(k0 + ty + j * 8) * N + n0 + tx];
  __syncthreads();
#pragma unroll
  for (int j = 0; j < 4; ++j) {
    int n = n0 + ty + j * 8;
    float s = (n < scale_cols) ? qscale : 1.0f;
    outT[(size_t)n * K + k0 + tx] = (bf16_t)(tile[tx][ty + j * 8] * s);
  }
}

// ---------------------------------------------------------------------------
// Deep-pipelined GEMM (round-9 proven version): C[M,N] = A[M,K] @ Bt[N,K]^T.
// BM=128, BN=256, BK=64. 512 threads = 8 waves (2M x 4N), per-wave 64x64.
// Triple-buffered LDS, 2-tile prefetch lead, ONE s_barrier + vmcnt(6)/tile,
// both-sides XOR swizzle (rule 21).
// ---------------------------------------------------------------------------
template <typename OutT>
__global__ __launch_bounds__(512, 2) void gemm_dp_kernel(
    const bf16_t* __restrict__ A, const bf16_t* __restrict__ Bt,
    OutT* __restrict__ C, int M, int N, int K, int NB) {
  __shared__ __align__(16) bf16_t As[3][128 * 64];  // 48 KiB
  __shared__ __align__(16) bf16_t Bs[3][256 * 64];  // 96 KiB

  const int tid = threadIdx.x;
  const int lane = tid & 63;
  const int wid = tid >> 6;  // 0..7
  const int l16 = lane & 15;
  const int g4 = lane >> 4;
  const int wm = wid >> 2;   // 0..1
  const int wn = wid & 3;    // 0..3
  const int tiles = K >> 6;  // K-tiles of 64

  const int nwg = gridDim.x;
  const int bid = blockIdx.x;
  const int swz = (bid & 7) * (nwg >> 3) + (bid >> 3);
  const int m0 = (swz / NB) * 128;
  const int n0 = (swz % NB) * 256;

  const int srow = tid >> 3;                              // 0..63
  const int scol = ((tid & 7) ^ (srow & 7)) * 8;          // swizzled source
  const bf16_t* aglob = A + (size_t)(m0 + srow) * K + scol;
  const bf16_t* bglob = Bt + (size_t)(n0 + srow) * K + scol;

  auto stage = [&](int t) {
    const int buf = t % 3;
    const int k0 = t * 64;
#pragma unroll
    for (int i = 0; i < 2; ++i)
      gload_lds16(aglob + (size_t)i * 64 * K + k0,
                  &As[buf][i * 4096 + wid * 512]);
#pragma unroll
    for (int j = 0; j < 4; ++j)
      gload_lds16(bglob + (size_t)j * 64 * K + k0,
                  &Bs[buf][j * 4096 + wid * 512]);
  };

  f32x4 acc[4][4] = {};

  stage(0);
  stage(1);
  asm volatile("s_waitcnt vmcnt(6)" ::: "memory");
  __builtin_amdgcn_s_barrier();
  __builtin_amdgcn_sched_barrier(0);

  const int xr = l16 & 7;  // read-side swizzle key

  for (int t = 0; t < tiles; ++t) {
    const int buf = t % 3;

    bf16x8 af[4][2], bff[4][2];
#pragma unroll
    for (int m = 0; m < 4; ++m)
#pragma unroll
      for (int ks = 0; ks < 2; ++ks)
        af[m][ks] = *reinterpret_cast<const bf16x8*>(
            &As[buf][(wm * 64 + m * 16 + l16) * 64 +
                     ((ks * 4 + g4) ^ xr) * 8]);
#pragma unroll
    for (int n = 0; n < 4; ++n)
#pragma unroll
      for (int ks = 0; ks < 2; ++ks)
        bff[n][ks] = *reinterpret_cast<const bf16x8*>(
            &Bs[buf][(wn * 64 + n * 16 + l16) * 64 +
                     ((ks * 4 + g4) ^ xr) * 8]);

    if (t + 2 < tiles) stage(t + 2);

    __builtin_amdgcn_s_setprio(1);
#pragma unroll
    for (int m = 0; m < 4; ++m)
#pragma unroll
      for (int n = 0; n < 4; ++n)
#pragma unroll
        for (int ks = 0; ks < 2; ++ks)
          acc[m][n] = __builtin_amdgcn_mfma_f32_16x16x32_bf16(
              af[m][ks], bff[n][ks], acc[m][n], 0, 0, 0);
    __builtin_amdgcn_s_setprio(0);

    if (t + 2 < tiles)
      asm volatile("s_waitcnt vmcnt(6)" ::: "memory");
    else
      asm volatile("s_waitcnt vmcnt(0)" ::: "memory");
    __builtin_amdgcn_s_barrier();
    __builtin_amdgcn_sched_barrier(0);
  }

#pragma unroll
  for (int m = 0; m < 4; ++m)
#pragma unroll
    for (int n = 0; n < 4; ++n)
#pragma unroll
      for (int r = 0; r < 4; ++r) {
        int row = m0 + wm * 64 + m * 16 + g4 * 4 + r;
        int col = n0 + wn * 64 + n * 16 + l16;
        C[(size_t)row * N + col] = (OutT)acc[m][n][r];
      }
}

// ---------------------------------------------------------------------------
// Flash attention body, QBLK=32 (2 q-blocks): one 128-key step, K issued LATE
// (post-QK) for a full-iteration prefetch lead with one kf register set.
// Halved q-tile cuts regs (qf/sA/sB/pf/acc_o/acc_l) ~80 -> higher occupancy.
// P pack via v_perm_b32 (RTZ bf16); row-sum l via ones-MFMA into acc_l.
// ---------------------------------------------------------------------------
template <bool PRE>
__device__ __forceinline__ void attn_body(
    const bf16_t* kp_next, const bf16_t* vp_next, bf16_t* vst_next,
    unsigned vrd, uint32x4 (&kf)[2][2], const bf16x8 (&qf)[2][2],
    const bf16x8 vones, f32x4 (&acc_o)[8], f32x4 (&acc_l)[2]) {
  if constexpr (PRE) {
#pragma unroll
    for (int t = 0; t < 4; ++t)
      gload_lds16(vp_next + t * 16, vst_next + t * 512);
  }

  if constexpr (PRE)
    asm volatile("s_waitcnt vmcnt(8)" ::: "memory");
  else
    asm volatile("s_waitcnt vmcnt(4)" ::: "memory");
  __builtin_amdgcn_sched_barrier(0);

  uint32x2 vr[4][2];
#define TRR(dst, OFFSTR)                              \
  asm volatile("ds_read_b64_tr_b16 %0, %1 offset:" OFFSTR \
               : "=v"(dst)                            \
               : "v"(vrd))
  TRR(vr[0][0], "0");    TRR(vr[0][1], "512");
  TRR(vr[1][0], "1024"); TRR(vr[1][1], "1536");
  TRR(vr[2][0], "2048"); TRR(vr[2][1], "2560");
  TRR(vr[3][0], "3072"); TRR(vr[3][1], "3584");
#undef TRR

  if constexpr (PRE)
    asm volatile("s_waitcnt vmcnt(4)" ::: "memory");
  else
    asm volatile("s_waitcnt vmcnt(0)" ::: "memory");
  __builtin_amdgcn_sched_barrier(0);  // rule 18

  f32x4 sA[2] = {}, sB[2] = {};
#pragma unroll
  for (int qb = 0; qb < 2; ++qb) {
    sA[qb] = __builtin_amdgcn_mfma_f32_16x16x32_bf16(
        __builtin_bit_cast(bf16x8, kf[0][0]), qf[qb][0], sA[qb], 0, 0, 0);
    sA[qb] = __builtin_amdgcn_mfma_f32_16x16x32_bf16(
        __builtin_bit_cast(bf16x8, kf[0][1]), qf[qb][1], sA[qb], 0, 0, 0);
    sB[qb] = __builtin_amdgcn_mfma_f32_16x16x32_bf16(
        __builtin_bit_cast(bf16x8, kf[1][0]), qf[qb][0], sB[qb], 0, 0, 0);
    sB[qb] = __builtin_amdgcn_mfma_f32_16x16x32_bf16(
        __builtin_bit_cast(bf16x8, kf[1][1]), qf[qb][1], sB[qb], 0, 0, 0);
  }

  if constexpr (PRE) {
#pragma unroll
    for (int half = 0; half < 2; ++half)
#pragma unroll
      for (int kh = 0; kh < 2; ++kh)
        asm volatile("global_load_dwordx4 %0, %1, off"
                     : "=v"(kf[half][kh])
                     : "v"(kp_next + (size_t)half * 64 * RSQ + kh * 32)
                     : "memory");
  }

  // exp2 -> v_perm_b32 pack (RTZ bf16; byte order explicit)
  const unsigned psel = 0x07060302u;
  bf16x8 pf[2];
#pragma unroll
  for (int qb = 0; qb < 2; ++qb) {
    unsigned b0 = __builtin_bit_cast(unsigned, __builtin_amdgcn_exp2f(sA[qb][0]));
    unsigned b1 = __builtin_bit_cast(unsigned, __builtin_amdgcn_exp2f(sA[qb][1]));
    unsigned b2 = __builtin_bit_cast(unsigned, __builtin_amdgcn_exp2f(sA[qb][2]));
    unsigned b3 = __builtin_bit_cast(unsigned, __builtin_amdgcn_exp2f(sA[qb][3]));
    unsigned b4 = __builtin_bit_cast(unsigned, __builtin_amdgcn_exp2f(sB[qb][0]));
    unsigned b5 = __builtin_bit_cast(unsigned, __builtin_amdgcn_exp2f(sB[qb][1]));
    unsigned b6 = __builtin_bit_cast(unsigned, __builtin_amdgcn_exp2f(sB[qb][2]));
    unsigned b7 = __builtin_bit_cast(unsigned, __builtin_amdgcn_exp2f(sB[qb][3]));
    unsigned u0, u1, u2, u3;
    asm("v_perm_b32 %0, %1, %2, %3" : "=v"(u0) : "v"(b1), "v"(b0), "v"(psel));
    asm("v_perm_b32 %0, %1, %2, %3" : "=v"(u1) : "v"(b3), "v"(b2), "v"(psel));
    asm("v_perm_b32 %0, %1, %2, %3" : "=v"(u2) : "v"(b5), "v"(b4), "v"(psel));
    asm("v_perm_b32 %0, %1, %2, %3" : "=v"(u3) : "v"(b7), "v"(b6), "v"(psel));
    uint32x4 pu = {u0, u1, u2, u3};
    pf[qb] = __builtin_bit_cast(bf16x8, pu);
  }

  asm volatile("s_waitcnt lgkmcnt(0)" ::: "memory");
  __builtin_amdgcn_sched_barrier(0);
  bf16x8 vf[4];
#pragma unroll
  for (int db = 0; db < 4; ++db) {
    uint32x4 c = {vr[db][0].x, vr[db][0].y, vr[db][1].x, vr[db][1].y};
    vf[db] = __builtin_bit_cast(bf16x8, c);
  }
#pragma unroll
  for (int qb = 0; qb < 2; ++qb) {
    acc_l[qb] = __builtin_amdgcn_mfma_f32_16x16x32_bf16(
        pf[qb], vones, acc_l[qb], 0, 0, 0);
#pragma unroll
    for (int db = 0; db < 4; ++db)
      acc_o[qb * 4 + db] = __builtin_amdgcn_mfma_f32_16x16x32_bf16(
          pf[qb], vf[db], acc_o[qb * 4 + db], 0, 0, 0);
  }
}

// ---------------------------------------------------------------------------
// Block = (b, h, 32 q-rows), 4 waves key-split, grid 4096 (XCD-swizzled).
// ---------------------------------------------------------------------------
__global__ __launch_bounds__(256) void attn_kernel(
    const bf16_t* __restrict__ qkv, bf16_t* __restrict__ out) {
  __shared__ __align__(16) unsigned char smem[33792];
  bf16_t* Vlds = (bf16_t*)smem;            // [4 waves][2 bufs][2048] = 32 KiB
  float(*Obuf)[66] = (float(*)[66])smem;   // [32][66], aliases Vlds
  float* lbuf = (float*)(smem + 32768);    // [4][32] floats

  const int tid = threadIdx.x;
  const int lane = tid & 63;
  const int wid = tid >> 6;
  const int l16 = lane & 15;
  const int g4 = lane >> 4;

  // XCD-aware decode: D = gg(3b) | qtile(6b) | xcd(3b); bh = gg*8+xcd
  const int D = blockIdx.x;
  const int g = ((D >> 9) << 3) + (D & 7);
  const int h = g & 15;
  const int b = g >> 4;
  const int q0 = ((D >> 3) & 63) * 32;

  const size_t base = (size_t)b * SEQ * RSQ;

  // ---- Q fragments (pre-scaled by 0.125*log2e via w_qkv), hoisted
  bf16x8 qf[2][2];
#pragma unroll
  for (int qb = 0; qb < 2; ++qb)
#pragma unroll
    for (int kh = 0; kh < 2; ++kh)
      qf[qb][kh] = __builtin_bit_cast(
          bf16x8, *reinterpret_cast<const uint4*>(
                      qkv + base + (size_t)(q0 + qb * 16 + l16) * RSQ + h * DH +
                      kh * 32 + g4 * 8));

  const bf16_t* kbase =
      qkv + base + (size_t)(wid * 16 + l16) * RSQ + DM + h * DH + g4 * 8;

  // V staging source (pre-swizzled: linear LDS == [db][eh][g4][j][l16])
  const int keyoff = ((lane >> 5) << 6) + wid * 16 + (((lane >> 3) & 3) << 2) +
                     ((lane >> 1) & 3);
  const bf16_t* vsrc =
      qkv + base + (size_t)keyoff * RSQ + 2 * DM + h * DH + (lane & 1) * 8;
  bf16_t* vwave = Vlds + wid * 4096;  // 2 buffers of 2048
  const unsigned vlane = lds_b32addr(vwave) + (lane << 3);

  bf16x8 vones;
#pragma unroll
  for (int e = 0; e < 8; ++e) vones[e] = (bf16_t)1.0f;

  f32x4 acc_o[8] = {};
  f32x4 acc_l[2] = {};
  uint32x4 kf[2][2];

  // ---- prologue: stage V(0) FIRST (must be older than K(0)), then K(0)
#pragma unroll
  for (int t = 0; t < 4; ++t) gload_lds16(vsrc + t * 16, vwave + t * 512);
#pragma unroll
  for (int half = 0; half < 2; ++half)
#pragma unroll
    for (int kh = 0; kh < 2; ++kh)
      asm volatile("global_load_dwordx4 %0, %1, off"
                   : "=v"(kf[half][kh])
                   : "v"(kbase + (size_t)half * 64 * RSQ + kh * 32)
                   : "memory");

  // ---- pipelined k-loop: bodies 0..14 prefetch K(i+1)/V(i+1); body 15 drains
  for (int i = 0; i < 15; ++i) {
    attn_body<true>(kbase + (size_t)(i + 1) * 128 * RSQ,
                    vsrc + (size_t)(i + 1) * 128 * RSQ,
                    vwave + ((i + 1) & 1) * 2048, vlane + (i & 1) * 4096, kf,
                    qf, vones, acc_o, acc_l);
  }
  attn_body<false>(nullptr, nullptr, nullptr, vlane + 4096, kf, qf, vones,
                   acc_o, acc_l);

  // ---- per-wave l partials (acc_l[qb][r] = l for q=qb*16+g4*4+r, any col)
  if (l16 == 0) {
#pragma unroll
    for (int qb = 0; qb < 2; ++qb)
#pragma unroll
      for (int r = 0; r < 4; ++r)
        lbuf[wid * 32 + qb * 16 + g4 * 4 + r] = acc_l[qb][r];
  }

  // ---- cross-wave O reduction (Obuf aliases Vlds; safe: vmem drained)
  for (int ph = 0; ph < 4; ++ph) {
    __syncthreads();
    if (wid == ph) {
#pragma unroll
      for (int qb = 0; qb < 2; ++qb)
#pragma unroll
        for (int db = 0; db < 4; ++db)
#pragma unroll
          for (int r = 0; r < 4; ++r) {
            int q = qb * 16 + g4 * 4 + r;
            int d = db * 16 + l16;
            if (ph == 0)
              Obuf[q][d] = acc_o[qb * 4 + db][r];
            else
              Obuf[q][d] += acc_o[qb * 4 + db][r];
          }
    }
  }
  __syncthreads();

  // ---- epilogue: 32 rows x 64 cols; thread = (row = tid>>3, 8-col chunk)
  {
    int row = tid >> 3;             // 0..31
    int cb = (tid & 7) * 8;         // 0,8,...,56
    float l = lbuf[0 * 32 + row] + lbuf[1 * 32 + row] + lbuf[2 * 32 + row] +
              lbuf[3 * 32 + row];
    float inv = 1.f / l;
    bf16_t ob[8];
#pragma unroll
    for (int c = 0; c < 8; ++c)
      ob[c] = (bf16_t)(Obuf[row][cb + c] * inv);
    bf16_t* op = out + (size_t)(b * SEQ + q0 + row) * DM + h * DH + cb;
    *reinterpret_cast<uint4*>(op) = *reinterpret_cast<const uint4*>(&ob[0]);
  }
}

// ---------------------------------------------------------------------------
extern "C" void kernel_launch(void* const* d_in, const int* in_sizes, int n_in,
                              void* d_out, int out_size, void* d_ws, size_t ws_size,
                              hipStream_t stream) {
  const float* x = (const float*)d_in[0];       // [4,2048,1024] fp32
  const float* w_qkv = (const float*)d_in[1];   // [1024,3072] fp32
  const float* w_o = (const float*)d_in[2];     // [1024,1024] fp32
  float* out = (float*)d_out;                   // [4,2048,1024] fp32

  bf16_t* xb = (bf16_t*)d_ws;                        // [8192][1024]
  bf16_t* wqkvt = xb + (size_t)8192 * 1024;          // [3072][1024]
  bf16_t* wot = wqkvt + (size_t)3072 * 1024;         // [1024][1024]
  bf16_t* qkv = wot + (size_t)1024 * 1024;           // [8192][3072]
  bf16_t* attn = qkv + (size_t)8192 * 3072;          // [8192][1024]

  const float c_exp2 = 0.18033688011112042f;  // 0.125 * log2(e)

  // merged prep: convert x + transpose(+q-scale) both weights, one launch
  prep_kernel<<<12288, 256, 0, stream>>>(x, xb, w_qkv, wqkvt, w_o, wot,
                                         c_exp2);

  // qkv = x @ w_qkv : 64x12 = 768 blocks (3 exact CU rounds)
  gemm_dp_kernel<bf16_t><<<768, 512, 0, stream>>>(
      xb, wqkvt, qkv, 8192, 3072, 1024, 12);
  attn_kernel<<<4096, 256, 0, stream>>>(qkv, attn);
  // out = attn @ w_o : 64x4 = 256 blocks (1 exact CU round)
  gemm_dp_kernel<float><<<256, 512, 0, stream>>>(
      attn, wot, out, 8192, 1024, 1024, 4);
}

// Round 16
// 215.189 us; speedup vs baseline: 1.3982x; 1.3982x over previous
//
#include <hip/hip_runtime.h>
#include <hip/hip_bf16.h>

typedef __bf16 bf16_t;
typedef __bf16 bf16x8 __attribute__((ext_vector_type(8)));
typedef float f32x4 __attribute__((ext_vector_type(4)));
typedef unsigned int uint32x2 __attribute__((ext_vector_type(2)));
typedef unsigned int uint32x4 __attribute__((ext_vector_type(4)));

#define B_SZ 4
#define SEQ 2048
#define NH 16
#define DH 64
#define DM 1024
#define RSQ (3 * DM)

// async global->LDS, 16B per lane. LDS dest = wave-uniform base + lane*16.
__device__ __forceinline__ void gload_lds16(const bf16_t* g, bf16_t* l) {
  __builtin_amdgcn_global_load_lds(
      (const __attribute__((address_space(1))) unsigned int*)g,
      (__attribute__((address_space(3))) unsigned int*)l, 16, 0, 0);
}

__device__ __forceinline__ unsigned lds_b32addr(void* p) {
  return (unsigned)(uintptr_t)(__attribute__((address_space(3))) void*)p;
}

// ---------------------------------------------------------------------------
// Merged prep: [0,8192) fp32->bf16 convert of x; [8192,11264) transpose+scale
// w_qkv; [11264,12288) transpose w_o. One launch instead of three.
// ---------------------------------------------------------------------------
__global__ __launch_bounds__(256) void prep_kernel(
    const float* __restrict__ x, bf16_t* __restrict__ xb,
    const float* __restrict__ w_qkv, bf16_t* __restrict__ wqkvt,
    const float* __restrict__ w_o, bf16_t* __restrict__ wot, float qscale) {
  __shared__ float tile[32][33];
  const int bid = blockIdx.x;
  if (bid < 8192) {
    int i = (bid * 256 + threadIdx.x) * 4;
    float4 v = *reinterpret_cast<const float4*>(x + i);
    bf16_t o[4] = {(bf16_t)v.x, (bf16_t)v.y, (bf16_t)v.z, (bf16_t)v.w};
    *reinterpret_cast<uint2*>(xb + i) = *reinterpret_cast<const uint2*>(o);
    return;
  }
  const float* in;
  bf16_t* outT;
  int K = 1024, N, n0, k0, scale_cols;
  if (bid < 8192 + 3072) {
    int i = bid - 8192;
    in = w_qkv; outT = wqkvt; N = 3072;
    n0 = (i % 96) * 32; k0 = (i / 96) * 32; scale_cols = 1024;
  } else {
    int i = bid - 8192 - 3072;
    in = w_o; outT = wot; N = 1024;
    n0 = (i % 32) * 32; k0 = (i / 32) * 32; scale_cols = 0;
  }
  const int tx = threadIdx.x & 31;
  const int ty = threadIdx.x >> 5;  // 0..7
#pragma unroll
  for (int j = 0; j < 4; ++j)
    tile[ty + j * 8][tx] = in[(size_t)(k0 + ty + j * 8) * N + n0 + tx];
  __syncthreads();
#pragma unroll
  for (int j = 0; j < 4; ++j) {
    int n = n0 + ty + j * 8;
    float s = (n < scale_cols) ? qscale : 1.0f;
    outT[(size_t)n * K + k0 + tx] = (bf16_t)(tile[tx][ty + j * 8] * s);
  }
}

// ---------------------------------------------------------------------------
// Deep-pipelined GEMM (round-9 proven version): C[M,N] = A[M,K] @ Bt[N,K]^T.
// BM=128, BN=256, BK=64. 512 threads = 8 waves (2M x 4N), per-wave 64x64.
// Triple-buffered LDS, 2-tile prefetch lead, ONE s_barrier + vmcnt(6)/tile,
// both-sides XOR swizzle (rule 21).
// ---------------------------------------------------------------------------
template <typename OutT>
__global__ __launch_bounds__(512, 2) void gemm_dp_kernel(
    const bf16_t* __restrict__ A, const bf16_t* __restrict__ Bt,
    OutT* __restrict__ C, int M, int N, int K, int NB) {
  __shared__ __align__(16) bf16_t As[3][128 * 64];  // 48 KiB
  __shared__ __align__(16) bf16_t Bs[3][256 * 64];  // 96 KiB

  const int tid = threadIdx.x;
  const int lane = tid & 63;
  const int wid = tid >> 6;  // 0..7
  const int l16 = lane & 15;
  const int g4 = lane >> 4;
  const int wm = wid >> 2;   // 0..1
  const int wn = wid & 3;    // 0..3
  const int tiles = K >> 6;  // K-tiles of 64

  const int nwg = gridDim.x;
  const int bid = blockIdx.x;
  const int swz = (bid & 7) * (nwg >> 3) + (bid >> 3);
  const int m0 = (swz / NB) * 128;
  const int n0 = (swz % NB) * 256;

  const int srow = tid >> 3;                              // 0..63
  const int scol = ((tid & 7) ^ (srow & 7)) * 8;          // swizzled source
  const bf16_t* aglob = A + (size_t)(m0 + srow) * K + scol;
  const bf16_t* bglob = Bt + (size_t)(n0 + srow) * K + scol;

  auto stage = [&](int t) {
    const int buf = t % 3;
    const int k0 = t * 64;
#pragma unroll
    for (int i = 0; i < 2; ++i)
      gload_lds16(aglob + (size_t)i * 64 * K + k0,
                  &As[buf][i * 4096 + wid * 512]);
#pragma unroll
    for (int j = 0; j < 4; ++j)
      gload_lds16(bglob + (size_t)j * 64 * K + k0,
                  &Bs[buf][j * 4096 + wid * 512]);
  };

  f32x4 acc[4][4] = {};

  stage(0);
  stage(1);
  asm volatile("s_waitcnt vmcnt(6)" ::: "memory");
  __builtin_amdgcn_s_barrier();
  __builtin_amdgcn_sched_barrier(0);

  const int xr = l16 & 7;  // read-side swizzle key

  for (int t = 0; t < tiles; ++t) {
    const int buf = t % 3;

    bf16x8 af[4][2], bff[4][2];
#pragma unroll
    for (int m = 0; m < 4; ++m)
#pragma unroll
      for (int ks = 0; ks < 2; ++ks)
        af[m][ks] = *reinterpret_cast<const bf16x8*>(
            &As[buf][(wm * 64 + m * 16 + l16) * 64 +
                     ((ks * 4 + g4) ^ xr) * 8]);
#pragma unroll
    for (int n = 0; n < 4; ++n)
#pragma unroll
      for (int ks = 0; ks < 2; ++ks)
        bff[n][ks] = *reinterpret_cast<const bf16x8*>(
            &Bs[buf][(wn * 64 + n * 16 + l16) * 64 +
                     ((ks * 4 + g4) ^ xr) * 8]);

    if (t + 2 < tiles) stage(t + 2);

    __builtin_amdgcn_s_setprio(1);
#pragma unroll
    for (int m = 0; m < 4; ++m)
#pragma unroll
      for (int n = 0; n < 4; ++n)
#pragma unroll
        for (int ks = 0; ks < 2; ++ks)
          acc[m][n] = __builtin_amdgcn_mfma_f32_16x16x32_bf16(
              af[m][ks], bff[n][ks], acc[m][n], 0, 0, 0);
    __builtin_amdgcn_s_setprio(0);

    if (t + 2 < tiles)
      asm volatile("s_waitcnt vmcnt(6)" ::: "memory");
    else
      asm volatile("s_waitcnt vmcnt(0)" ::: "memory");
    __builtin_amdgcn_s_barrier();
    __builtin_amdgcn_sched_barrier(0);
  }

#pragma unroll
  for (int m = 0; m < 4; ++m)
#pragma unroll
    for (int n = 0; n < 4; ++n)
#pragma unroll
      for (int r = 0; r < 4; ++r) {
        int row = m0 + wm * 64 + m * 16 + g4 * 4 + r;
        int col = n0 + wn * 64 + n * 16 + l16;
        C[(size_t)row * N + col] = (OutT)acc[m][n][r];
      }
}

// ---------------------------------------------------------------------------
// Flash attention body (round-12/14 proven version): one 128-key step, K
// issued LATE (post-QK) for a full-iteration prefetch lead with one kf set.
// P pack via v_perm_b32 (RTZ bf16); row-sum l via ones-MFMA into acc_l.
// ---------------------------------------------------------------------------
template <bool PRE>
__device__ __forceinline__ void attn_body(
    const bf16_t* kp_next, const bf16_t* vp_next, bf16_t* vst_next,
    unsigned vrd, uint32x4 (&kf)[2][2], const bf16x8 (&qf)[4][2],
    const bf16x8 vones, f32x4 (&acc_o)[16], f32x4 (&acc_l)[4]) {
  if constexpr (PRE) {
#pragma unroll
    for (int t = 0; t < 4; ++t)
      gload_lds16(vp_next + t * 16, vst_next + t * 512);
  }

  if constexpr (PRE)
    asm volatile("s_waitcnt vmcnt(8)" ::: "memory");
  else
    asm volatile("s_waitcnt vmcnt(4)" ::: "memory");
  __builtin_amdgcn_sched_barrier(0);

  uint32x2 vr[4][2];
#define TRR(dst, OFFSTR)                              \
  asm volatile("ds_read_b64_tr_b16 %0, %1 offset:" OFFSTR \
               : "=v"(dst)                            \
               : "v"(vrd))
  TRR(vr[0][0], "0");    TRR(vr[0][1], "512");
  TRR(vr[1][0], "1024"); TRR(vr[1][1], "1536");
  TRR(vr[2][0], "2048"); TRR(vr[2][1], "2560");
  TRR(vr[3][0], "3072"); TRR(vr[3][1], "3584");
#undef TRR

  if constexpr (PRE)
    asm volatile("s_waitcnt vmcnt(4)" ::: "memory");
  else
    asm volatile("s_waitcnt vmcnt(0)" ::: "memory");
  __builtin_amdgcn_sched_barrier(0);  // rule 18

  f32x4 sA[4] = {}, sB[4] = {};
#pragma unroll
  for (int qb = 0; qb < 4; ++qb) {
    sA[qb] = __builtin_amdgcn_mfma_f32_16x16x32_bf16(
        __builtin_bit_cast(bf16x8, kf[0][0]), qf[qb][0], sA[qb], 0, 0, 0);
    sA[qb] = __builtin_amdgcn_mfma_f32_16x16x32_bf16(
        __builtin_bit_cast(bf16x8, kf[0][1]), qf[qb][1], sA[qb], 0, 0, 0);
    sB[qb] = __builtin_amdgcn_mfma_f32_16x16x32_bf16(
        __builtin_bit_cast(bf16x8, kf[1][0]), qf[qb][0], sB[qb], 0, 0, 0);
    sB[qb] = __builtin_amdgcn_mfma_f32_16x16x32_bf16(
        __builtin_bit_cast(bf16x8, kf[1][1]), qf[qb][1], sB[qb], 0, 0, 0);
  }

  if constexpr (PRE) {
#pragma unroll
    for (int half = 0; half < 2; ++half)
#pragma unroll
      for (int kh = 0; kh < 2; ++kh)
        asm volatile("global_load_dwordx4 %0, %1, off"
                     : "=v"(kf[half][kh])
                     : "v"(kp_next + (size_t)half * 64 * RSQ + kh * 32)
                     : "memory");
  }

  // exp2 -> v_perm_b32 pack (RTZ bf16; byte order explicit)
  const unsigned psel = 0x07060302u;
  bf16x8 pf[4];
#pragma unroll
  for (int qb = 0; qb < 4; ++qb) {
    unsigned b0 = __builtin_bit_cast(unsigned, __builtin_amdgcn_exp2f(sA[qb][0]));
    unsigned b1 = __builtin_bit_cast(unsigned, __builtin_amdgcn_exp2f(sA[qb][1]));
    unsigned b2 = __builtin_bit_cast(unsigned, __builtin_amdgcn_exp2f(sA[qb][2]));
    unsigned b3 = __builtin_bit_cast(unsigned, __builtin_amdgcn_exp2f(sA[qb][3]));
    unsigned b4 = __builtin_bit_cast(unsigned, __builtin_amdgcn_exp2f(sB[qb][0]));
    unsigned b5 = __builtin_bit_cast(unsigned, __builtin_amdgcn_exp2f(sB[qb][1]));
    unsigned b6 = __builtin_bit_cast(unsigned, __builtin_amdgcn_exp2f(sB[qb][2]));
    unsigned b7 = __builtin_bit_cast(unsigned, __builtin_amdgcn_exp2f(sB[qb][3]));
    unsigned u0, u1, u2, u3;
    asm("v_perm_b32 %0, %1, %2, %3" : "=v"(u0) : "v"(b1), "v"(b0), "v"(psel));
    asm("v_perm_b32 %0, %1, %2, %3" : "=v"(u1) : "v"(b3), "v"(b2), "v"(psel));
    asm("v_perm_b32 %0, %1, %2, %3" : "=v"(u2) : "v"(b5), "v"(b4), "v"(psel));
    asm("v_perm_b32 %0, %1, %2, %3" : "=v"(u3) : "v"(b7), "v"(b6), "v"(psel));
    uint32x4 pu = {u0, u1, u2, u3};
    pf[qb] = __builtin_bit_cast(bf16x8, pu);
  }

  asm volatile("s_waitcnt lgkmcnt(0)" ::: "memory");
  __builtin_amdgcn_sched_barrier(0);
  bf16x8 vf[4];
#pragma unroll
  for (int db = 0; db < 4; ++db) {
    uint32x4 c = {vr[db][0].x, vr[db][0].y, vr[db][1].x, vr[db][1].y};
    vf[db] = __builtin_bit_cast(bf16x8, c);
  }
#pragma unroll
  for (int qb = 0; qb < 4; ++qb) {
    acc_l[qb] = __builtin_amdgcn_mfma_f32_16x16x32_bf16(
        pf[qb], vones, acc_l[qb], 0, 0, 0);
#pragma unroll
    for (int db = 0; db < 4; ++db)
      acc_o[qb * 4 + db] = __builtin_amdgcn_mfma_f32_16x16x32_bf16(
          pf[qb], vf[db], acc_o[qb * 4 + db], 0, 0, 0);
  }
}

// ---------------------------------------------------------------------------
__global__ __launch_bounds__(256) void attn_kernel(
    const bf16_t* __restrict__ qkv, bf16_t* __restrict__ out) {
  __shared__ __align__(16) unsigned char smem[33792];
  bf16_t* Vlds = (bf16_t*)smem;            // [4 waves][2 bufs][2048] = 32 KiB
  float(*Obuf)[66] = (float(*)[66])smem;   // aliases Vlds (k-loop finished)
  float* lbuf = (float*)(smem + 32768);    // [4][64] floats

  const int tid = threadIdx.x;
  const int lane = tid & 63;
  const int wid = tid >> 6;
  const int l16 = lane & 15;
  const int g4 = lane >> 4;

  const int D = blockIdx.x;
  const int g = ((D >> 8) << 3) + (D & 7);
  const int h = g & 15;
  const int b = g >> 4;
  const int q0 = ((D >> 3) & 31) * 64;

  const size_t base = (size_t)b * SEQ * RSQ;

  bf16x8 qf[4][2];
#pragma unroll
  for (int qb = 0; qb < 4; ++qb)
#pragma unroll
    for (int kh = 0; kh < 2; ++kh)
      qf[qb][kh] = __builtin_bit_cast(
          bf16x8, *reinterpret_cast<const uint4*>(
                      qkv + base + (size_t)(q0 + qb * 16 + l16) * RSQ + h * DH +
                      kh * 32 + g4 * 8));

  const bf16_t* kbase =
      qkv + base + (size_t)(wid * 16 + l16) * RSQ + DM + h * DH + g4 * 8;

  const int keyoff = ((lane >> 5) << 6) + wid * 16 + (((lane >> 3) & 3) << 2) +
                     ((lane >> 1) & 3);
  const bf16_t* vsrc =
      qkv + base + (size_t)keyoff * RSQ + 2 * DM + h * DH + (lane & 1) * 8;
  bf16_t* vwave = Vlds + wid * 4096;  // 2 buffers of 2048
  const unsigned vlane = lds_b32addr(vwave) + (lane << 3);

  bf16x8 vones;
#pragma unroll
  for (int e = 0; e < 8; ++e) vones[e] = (bf16_t)1.0f;

  f32x4 acc_o[16] = {};
  f32x4 acc_l[4] = {};
  uint32x4 kf[2][2];

#pragma unroll
  for (int t = 0; t < 4; ++t) gload_lds16(vsrc + t * 16, vwave + t * 512);
#pragma unroll
  for (int half = 0; half < 2; ++half)
#pragma unroll
    for (int kh = 0; kh < 2; ++kh)
      asm volatile("global_load_dwordx4 %0, %1, off"
                   : "=v"(kf[half][kh])
                   : "v"(kbase + (size_t)half * 64 * RSQ + kh * 32)
                   : "memory");

  for (int i = 0; i < 15; ++i) {
    attn_body<true>(kbase + (size_t)(i + 1) * 128 * RSQ,
                    vsrc + (size_t)(i + 1) * 128 * RSQ,
                    vwave + ((i + 1) & 1) * 2048, vlane + (i & 1) * 4096, kf,
                    qf, vones, acc_o, acc_l);
  }
  attn_body<false>(nullptr, nullptr, nullptr, vlane + 4096, kf, qf, vones,
                   acc_o, acc_l);

  if (l16 == 0) {
#pragma unroll
    for (int qb = 0; qb < 4; ++qb)
#pragma unroll
      for (int r = 0; r < 4; ++r)
        lbuf[wid * 64 + qb * 16 + g4 * 4 + r] = acc_l[qb][r];
  }

  for (int ph = 0; ph < 4; ++ph) {
    __syncthreads();
    if (wid == ph) {
#pragma unroll
      for (int qb = 0; qb < 4; ++qb)
#pragma unroll
        for (int db = 0; db < 4; ++db)
#pragma unroll
          for (int r = 0; r < 4; ++r) {
            int q = qb * 16 + g4 * 4 + r;
            int d = db * 16 + l16;
            if (ph == 0)
              Obuf[q][d] = acc_o[qb * 4 + db][r];
            else
              Obuf[q][d] += acc_o[qb * 4 + db][r];
          }
    }
  }
  __syncthreads();

  {
    int q = wid * 16 + l16;
    float l = lbuf[0 * 64 + q] + lbuf[1 * 64 + q] + lbuf[2 * 64 + q] +
              lbuf[3 * 64 + q];
    float inv = 1.f / l;
    bf16_t ob[16];
#pragma unroll
    for (int c = 0; c < 16; ++c)
      ob[c] = (bf16_t)(Obuf[q][g4 * 16 + c] * inv);
    bf16_t* op = out + (size_t)(b * SEQ + q0 + q) * DM + h * DH + g4 * 16;
    *reinterpret_cast<uint4*>(op) = *reinterpret_cast<const uint4*>(&ob[0]);
    *reinterpret_cast<uint4*>(op + 8) = *reinterpret_cast<const uint4*>(&ob[8]);
  }
}

// ---------------------------------------------------------------------------
extern "C" void kernel_launch(void* const* d_in, const int* in_sizes, int n_in,
                              void* d_out, int out_size, void* d_ws, size_t ws_size,
                              hipStream_t stream) {
  const float* x = (const float*)d_in[0];       // [4,2048,1024] fp32
  const float* w_qkv = (const float*)d_in[1];   // [1024,3072] fp32
  const float* w_o = (const float*)d_in[2];     // [1024,1024] fp32
  float* out = (float*)d_out;                   // [4,2048,1024] fp32

  bf16_t* xb = (bf16_t*)d_ws;                        // [8192][1024]
  bf16_t* wqkvt = xb + (size_t)8192 * 1024;          // [3072][1024]
  bf16_t* wot = wqkvt + (size_t)3072 * 1024;         // [1024][1024]
  bf16_t* qkv = wot + (size_t)1024 * 1024;           // [8192][3072]
  bf16_t* attn = qkv + (size_t)8192 * 3072;          // [8192][1024]

  const float c_exp2 = 0.18033688011112042f;  // 0.125 * log2(e)

  // merged prep: convert x + transpose(+q-scale) both weights, one launch
  prep_kernel<<<12288, 256, 0, stream>>>(x, xb, w_qkv, wqkvt, w_o, wot,
                                         c_exp2);

  // qkv = x @ w_qkv : 64x12 = 768 blocks (3 exact CU rounds)
  gemm_dp_kernel<bf16_t><<<768, 512, 0, stream>>>(
      xb, wqkvt, qkv, 8192, 3072, 1024, 12);
  attn_kernel<<<2048, 256, 0, stream>>>(qkv, attn);
  // out = attn @ w_o : 64x4 = 256 blocks (1 exact CU round)
  gemm_dp_kernel<float><<<256, 512, 0, stream>>>(
      attn, wot, out, 8192, 1024, 1024, 4);
}